// Round 1
// baseline (421.077 us; speedup 1.0000x reference)
//
#include <hip/hip_runtime.h>

// LiquidTimeConstantCell fused kernel, MI355X gfx950 — R7.
// Same GEMM layout / math as R6 (transposed MFMA, bf16 GEMM inputs, fp32 state).
// CHANGES vs R6 (all latency/overlap, no layout change):
//   1. ROWS 64->32, grid 512->1024 (4 blocks/CU), __launch_bounds__(256,4):
//      4 waves/SIMD of independent work to fill barrier stalls (was 2).
//   2. Double-buffered ldsY: ONE __syncthreads per RK4 stage (was 2).
//      Buffer flip is static: S1 reads Y0/writes Y1, S2 reads Y1/writes Y0, ...
//   3. ode_out global stores issued right after the stage-1 barrier from live
//      h regs -> vmcnt(0) drain at the next barrier is hidden under a feval.
//   4. Branchless tanh: 1 - 2/(1+e^{2x}) (exact, saturates correctly at +-inf).

constexpr int kB   = 32768;
constexpr int kH   = 128;
constexpr int kIn  = 128;
constexpr int kT   = 10;
constexpr int ROWS = 32;     // batch rows per block -> 1024 blocks, 4 blocks/CU
constexpr int NT   = ROWS / 16;   // row-tiles per wave
constexpr int LDSW = 136;    // padded bf16 row stride
constexpr int HIN  = 256;    // H + IN

typedef __bf16 bf16;
typedef __attribute__((ext_vector_type(8))) __bf16 bf16x8;
typedef __attribute__((ext_vector_type(4))) __bf16 bf16x4;
typedef __attribute__((ext_vector_type(4))) float  f32x4;

__device__ __forceinline__ float sigmoid_(float v) {
  return __fdividef(1.0f, 1.0f + __expf(-v));
}
// tanh(v) = 1 - 2/(1 + e^{2v}); total for all v (e=inf -> 1, e=0 -> -1), branchless.
__device__ __forceinline__ float tanh_(float v) {
  float e = __expf(2.0f * v);
  return 1.0f - __fdividef(2.0f, 1.0f + e);
}

__device__ __forceinline__ bf16x8 cvt8(const float* p) {
  float4 f0 = *(const float4*)p;
  float4 f1 = *(const float4*)(p + 4);
  bf16x8 t;
  t[0]=(bf16)f0.x; t[1]=(bf16)f0.y; t[2]=(bf16)f0.z; t[3]=(bf16)f0.w;
  t[4]=(bf16)f1.x; t[5]=(bf16)f1.y; t[6]=(bf16)f1.z; t[7]=(bf16)f1.w;
  return t;
}

// C[a][nt] += bf16(Wb[hrow][kofs+k]) * S[r][k];  hrow=(2*wave+a)*16+l16 (A, m=l16),
// r = nt*16 + l16 (B, n=l16), k = kk*32 + quad*8 + j.
__device__ __forceinline__ void gemm4(
    f32x4 (&C)[2][NT], const bf16 (*S)[LDSW],
    const float* __restrict__ Wb, int ldw, int kofs,
    int wave, int quad, int l16)
{
#pragma unroll
  for (int kk = 0; kk < 4; ++kk) {
    bf16x8 af[2];
#pragma unroll
    for (int a = 0; a < 2; ++a)
      af[a] = cvt8(Wb + (size_t)((wave*2 + a)*16 + l16) * ldw + kofs + kk*32 + quad*8);
#pragma unroll
    for (int nt = 0; nt < NT; ++nt) {
      bf16x8 bfv = *(const bf16x8*)&S[nt*16 + l16][kk*32 + quad*8];
#pragma unroll
      for (int a = 0; a < 2; ++a)
        C[a][nt] = __builtin_amdgcn_mfma_f32_16x16x32_bf16(af[a], bfv, C[a][nt], 0, 0, 0);
    }
  }
}

// K = bias + Weff @ z^T, z read from Y (bf16)
__device__ __forceinline__ void feval(
    f32x4 (&K)[2][NT], const bf16x8 (&weff)[2][4], const bf16 (*Y)[LDSW],
    float4 bv0, float4 bv1, int quad, int l16)
{
#pragma unroll
  for (int nt = 0; nt < NT; ++nt) {
    K[0][nt] = f32x4{bv0.x, bv0.y, bv0.z, bv0.w};
    K[1][nt] = f32x4{bv1.x, bv1.y, bv1.z, bv1.w};
  }
#pragma unroll
  for (int kk = 0; kk < 4; ++kk)
#pragma unroll
    for (int nt = 0; nt < NT; ++nt) {
      bf16x8 bfv = *(const bf16x8*)&Y[nt*16 + l16][kk*32 + quad*8];
#pragma unroll
      for (int a = 0; a < 2; ++a)
        K[a][nt] = __builtin_amdgcn_mfma_f32_16x16x32_bf16(weff[a][kk], bfv, K[a][nt], 0, 0, 0);
    }
}

// store V to LDS Y[r][h] as bf16 (LDS only)
__device__ __forceinline__ void storeTile(
    bf16 (*Y)[LDSW], const f32x4 (&V)[2][NT], int hc0, int l16)
{
#pragma unroll
  for (int a = 0; a < 2; ++a)
#pragma unroll
    for (int nt = 0; nt < NT; ++nt) {
      bf16x4 p;
      p[0]=(bf16)V[a][nt][0]; p[1]=(bf16)V[a][nt][1];
      p[2]=(bf16)V[a][nt][2]; p[3]=(bf16)V[a][nt][3];
      *(bf16x4*)&Y[nt*16 + l16][hc0 + a*16] = p;
    }
}

// store V to global fp32, row-major [r][h], gbase pre-offset to block rows
__device__ __forceinline__ void storeGlob(
    float* gbase, const f32x4 (&V)[2][NT], int hc0, int l16)
{
#pragma unroll
  for (int a = 0; a < 2; ++a)
#pragma unroll
    for (int nt = 0; nt < NT; ++nt) {
      float4 g{V[a][nt][0], V[a][nt][1], V[a][nt][2], V[a][nt][3]};
      *(float4*)(gbase + (size_t)(nt*16 + l16) * kH + hc0 + a*16) = g;
    }
}

__global__ __launch_bounds__(256, 4) void ltc_kernel(
    const float* __restrict__ x,     const float* __restrict__ hidden,
    const float* __restrict__ ts,    const float* __restrict__ wiring,
    const float* __restrict__ W,     const float* __restrict__ bb_,
    const float* __restrict__ W_in,  const float* __restrict__ b_in,
    const float* __restrict__ W_upd, const float* __restrict__ b_upd,
    const float* __restrict__ W_rst, const float* __restrict__ b_rst,
    float* __restrict__ out)   // FP32 output: [new_hidden (B,H); ode_out (T,B,H)]
{
  __shared__ bf16 ldsX [ROWS][LDSW];   // x tile; later h0 (bf16)
  __shared__ bf16 ldsHd[ROWS][LDSW];   // hidden tile; later u (bf16)
  __shared__ bf16 ldsY0[ROWS][LDSW];   // ODE state z, ping
  __shared__ bf16 ldsY1[ROWS][LDSW];   // ODE state z, pong
  __shared__ float sts[kT];

  const int tid  = threadIdx.x;
  const int wave = tid >> 6;
  const int lane = tid & 63;
  const int quad = lane >> 4;
  const int l16  = lane & 15;
  const int r0   = blockIdx.x * ROWS;

  if (tid < kT) sts[tid] = ts[tid];

  // ---- stage x & hidden tiles into LDS as bf16 ----
#pragma unroll
  for (int i = 0; i < 4; ++i) {
    int idx = i*256 + tid;            // float4 index in 32x32
    int row = idx >> 5;
    int c4  = (idx & 31) * 4;
    float4 vx = *(const float4*)(x      + (size_t)(r0+row)*kIn + c4);
    float4 vh = *(const float4*)(hidden + (size_t)(r0+row)*kH  + c4);
    bf16x4 bx; bx[0]=(bf16)vx.x; bx[1]=(bf16)vx.y; bx[2]=(bf16)vx.z; bx[3]=(bf16)vx.w;
    bf16x4 bh; bh[0]=(bf16)vh.x; bh[1]=(bf16)vh.y; bh[2]=(bf16)vh.z; bh[3]=(bf16)vh.w;
    *(bf16x4*)&ldsX [row][c4] = bx;
    *(bf16x4*)&ldsHd[row][c4] = bh;
  }

  const int hc0 = wave*32 + quad*4;    // lane's C-tile h base (a=0; +16 for a=1)

  // ---- persistent W_eff = W .* wiring, A-fragments (32 VGPRs) ----
  bf16x8 weff[2][4];
#pragma unroll
  for (int a = 0; a < 2; ++a) {
    int hrow = (wave*2 + a)*16 + l16;
#pragma unroll
    for (int kk = 0; kk < 4; ++kk) {
      int k = kk*32 + quad*8;
      const float* wp = W      + (size_t)hrow*kH + k;
      const float* mp = wiring + (size_t)hrow*kH + k;
      float4 w0 = *(const float4*)wp, w1 = *(const float4*)(wp+4);
      float4 m0 = *(const float4*)mp, m1 = *(const float4*)(mp+4);
      bf16x8 t;
      t[0]=(bf16)(w0.x*m0.x); t[1]=(bf16)(w0.y*m0.y);
      t[2]=(bf16)(w0.z*m0.z); t[3]=(bf16)(w0.w*m0.w);
      t[4]=(bf16)(w1.x*m1.x); t[5]=(bf16)(w1.y*m1.y);
      t[6]=(bf16)(w1.z*m1.z); t[7]=(bf16)(w1.w*m1.w);
      weff[a][kk] = t;
    }
  }
  float4 bv0 = *(const float4*)(bb_ + hc0);
  float4 bv1 = *(const float4*)(bb_ + hc0 + 16);

  __syncthreads();   // x/hidden tiles visible

  // ---- x_proj (persistent regs) ----
  f32x4 xp[2][NT];
  {
    float4 bi0 = *(const float4*)(b_in + hc0);
    float4 bi1 = *(const float4*)(b_in + hc0 + 16);
#pragma unroll
    for (int nt = 0; nt < NT; ++nt) {
      xp[0][nt] = f32x4{bi0.x, bi0.y, bi0.z, bi0.w};
      xp[1][nt] = f32x4{bi1.x, bi1.y, bi1.z, bi1.w};
    }
    gemm4(xp, ldsX, W_in, kIn, 0, wave, quad, l16);
  }

  // ---- both gates up front ----
  f32x4 h[2][NT], U[2][NT];
  {
    f32x4 R[2][NT];
    float4 br0 = *(const float4*)(b_rst + hc0);
    float4 br1 = *(const float4*)(b_rst + hc0 + 16);
    float4 bu0 = *(const float4*)(b_upd + hc0);
    float4 bu1 = *(const float4*)(b_upd + hc0 + 16);
#pragma unroll
    for (int nt = 0; nt < NT; ++nt) {
      R[0][nt] = f32x4{br0.x, br0.y, br0.z, br0.w};
      R[1][nt] = f32x4{br1.x, br1.y, br1.z, br1.w};
      U[0][nt] = f32x4{bu0.x, bu0.y, bu0.z, bu0.w};
      U[1][nt] = f32x4{bu1.x, bu1.y, bu1.z, bu1.w};
    }
    gemm4(R, ldsHd, W_rst, HIN, 0,  wave, quad, l16);
    gemm4(R, ldsX,  W_rst, HIN, kH, wave, quad, l16);
    gemm4(U, ldsHd, W_upd, HIN, 0,  wave, quad, l16);
    gemm4(U, ldsX,  W_upd, HIN, kH, wave, quad, l16);

#pragma unroll
    for (int a = 0; a < 2; ++a)
#pragma unroll
      for (int nt = 0; nt < NT; ++nt) {
        const float* hp = hidden + (size_t)(r0 + nt*16 + l16)*kH + hc0 + a*16;
        float4 hv = *(const float4*)hp;
        h[a][nt][0] = sigmoid_(R[a][nt][0]) * hv.x;   // h0
        h[a][nt][1] = sigmoid_(R[a][nt][1]) * hv.y;
        h[a][nt][2] = sigmoid_(R[a][nt][2]) * hv.z;
        h[a][nt][3] = sigmoid_(R[a][nt][3]) * hv.w;
        U[a][nt][0] = sigmoid_(U[a][nt][0]);          // u
        U[a][nt][1] = sigmoid_(U[a][nt][1]);
        U[a][nt][2] = sigmoid_(U[a][nt][2]);
        U[a][nt][3] = sigmoid_(U[a][nt][3]);
      }
  }

  __syncthreads();   // gate GEMM reads of ldsX/ldsHd done -> tiles reusable

  // park u and h0 in the now-dead tiles (bf16), freeing registers for the loop
  storeTile(ldsHd, U, hc0, l16);
  storeTile(ldsX,  h, hc0, l16);
  storeTile(ldsY0, h, hc0, l16);      // z = h0 (ping buffer)

  f32x4 z[2][NT], hacc[2][NT], K[2][NT];
#pragma unroll
  for (int a = 0; a < 2; ++a)
#pragma unroll
    for (int nt = 0; nt < NT; ++nt) z[a][nt] = h[a][nt];

  float* odeBase = out + (size_t)kB*kH + (size_t)r0*kH;

  for (int t = 1; t < kT; ++t) {
    float dt  = sts[t] - sts[t-1];   // via LDS (R1: uniform global read ISel bug)
    float dt6 = dt * (1.0f/6.0f);
    float dt3 = dt * (1.0f/3.0f);
    float dth = 0.5f * dt;

    // ---- stage 1: read Y0, write Y1 ----
    __syncthreads();
    // deferred ode_out[t-1] = h_{t-1}: issued here, drains under this stage's
    // feval+pointwise instead of immediately before a barrier.
    storeGlob(odeBase + (size_t)(t-1)*kB*kH, h, hc0, l16);
    feval(K, weff, ldsY0, bv0, bv1, quad, l16);
#pragma unroll
    for (int a = 0; a < 2; ++a)
#pragma unroll
      for (int nt = 0; nt < NT; ++nt)
#pragma unroll
        for (int i = 0; i < 4; ++i) {
          float kv = tanh_(K[a][nt][i]) + xp[a][nt][i] - z[a][nt][i];
          hacc[a][nt][i] = h[a][nt][i] + dt6 * kv;
          z[a][nt][i]    = h[a][nt][i] + dth * kv;
        }
    storeTile(ldsY1, z, hc0, l16);

    // ---- stage 2: read Y1, write Y0 ----
    __syncthreads();
    feval(K, weff, ldsY1, bv0, bv1, quad, l16);
#pragma unroll
    for (int a = 0; a < 2; ++a)
#pragma unroll
      for (int nt = 0; nt < NT; ++nt)
#pragma unroll
        for (int i = 0; i < 4; ++i) {
          float kv = tanh_(K[a][nt][i]) + xp[a][nt][i] - z[a][nt][i];
          hacc[a][nt][i] += dt3 * kv;
          z[a][nt][i]     = h[a][nt][i] + dth * kv;
        }
    storeTile(ldsY0, z, hc0, l16);

    // ---- stage 3: read Y0, write Y1 ----
    __syncthreads();
    feval(K, weff, ldsY0, bv0, bv1, quad, l16);
#pragma unroll
    for (int a = 0; a < 2; ++a)
#pragma unroll
      for (int nt = 0; nt < NT; ++nt)
#pragma unroll
        for (int i = 0; i < 4; ++i) {
          float kv = tanh_(K[a][nt][i]) + xp[a][nt][i] - z[a][nt][i];
          hacc[a][nt][i] += dt3 * kv;
          z[a][nt][i]     = h[a][nt][i] + dt * kv;
        }
    storeTile(ldsY1, z, hc0, l16);

    // ---- stage 4: read Y1, write Y0 ----
    __syncthreads();
    feval(K, weff, ldsY1, bv0, bv1, quad, l16);
#pragma unroll
    for (int a = 0; a < 2; ++a)
#pragma unroll
      for (int nt = 0; nt < NT; ++nt)
#pragma unroll
        for (int i = 0; i < 4; ++i) {
          float kv = tanh_(K[a][nt][i]) + xp[a][nt][i] - z[a][nt][i];
          h[a][nt][i] = hacc[a][nt][i] + dt6 * kv;
          z[a][nt][i] = h[a][nt][i];
        }
    storeTile(ldsY0, z, hc0, l16);   // next step's stage 1 reads Y0
  }

  // last ode slab: ode_out[T-1] = h_last
  storeGlob(odeBase + (size_t)(kT-1)*kB*kH, h, hc0, l16);

  // ---- final blend: new_hidden = u*h_last + (1-u)*h0 (fp32 store) ----
  // parked u/h0 rectangles were written by this same wave -> no barrier needed
#pragma unroll
  for (int a = 0; a < 2; ++a)
#pragma unroll
    for (int nt = 0; nt < NT; ++nt) {
      int r = nt*16 + l16;
      bf16x4 uv  = *(const bf16x4*)&ldsHd[r][hc0 + a*16];
      bf16x4 h0v = *(const bf16x4*)&ldsX [r][hc0 + a*16];
      float4 p;
      {
        float uu;
        uu = (float)uv[0]; p.x = uu * h[a][nt][0] + (1.0f - uu) * (float)h0v[0];
        uu = (float)uv[1]; p.y = uu * h[a][nt][1] + (1.0f - uu) * (float)h0v[1];
        uu = (float)uv[2]; p.z = uu * h[a][nt][2] + (1.0f - uu) * (float)h0v[2];
        uu = (float)uv[3]; p.w = uu * h[a][nt][3] + (1.0f - uu) * (float)h0v[3];
      }
      *(float4*)(out + (size_t)(r0 + r) * kH + hc0 + a*16) = p;
    }
}

extern "C" void kernel_launch(void* const* d_in, const int* in_sizes, int n_in,
                              void* d_out, int out_size, void* d_ws, size_t ws_size,
                              hipStream_t stream) {
  (void)d_ws; (void)ws_size; (void)out_size;
  // Resolve input order from in_sizes (insurance; documented order expected).
  int ix=0, ih=1, its=2, iwr=3, iW=4, ib=5, iWin=6, ibin=7, iWu=8, ibu=9, iWr=10, ibr=11;
  if (n_in == 12 && in_sizes[2] != 10 && in_sizes[5] == 10) {
    // case-insensitive name-sorted: b,b_in,b_rst,b_upd,hidden,time_span,W,W_in,W_rst,W_upd,wiring,x
    ib=0; ibin=1; ibr=2; ibu=3; ih=4; its=5; iW=6; iWin=7; iWr=8; iWu=9; iwr=10; ix=11;
  }
  const float* x      = (const float*)d_in[ix];
  const float* hidden = (const float*)d_in[ih];
  const float* ts     = (const float*)d_in[its];
  const float* wiring = (const float*)d_in[iwr];
  const float* W      = (const float*)d_in[iW];
  const float* b      = (const float*)d_in[ib];
  const float* W_in   = (const float*)d_in[iWin];
  const float* b_in   = (const float*)d_in[ibin];
  const float* W_upd  = (const float*)d_in[iWu];
  const float* b_upd  = (const float*)d_in[ibu];
  const float* W_rst  = (const float*)d_in[iWr];
  const float* b_rst  = (const float*)d_in[ibr];

  dim3 grid(kB / ROWS);   // 1024 blocks -> 4 blocks/CU
  dim3 block(256);
  ltc_kernel<<<grid, block, 0, stream>>>(x, hidden, ts, wiring, W, b,
                                         W_in, b_in, W_upd, b_upd, W_rst, b_rst,
                                         (float*)d_out);
}

// Round 2
// 347.547 us; speedup vs baseline: 1.2116x; 1.2116x over previous
//
#include <hip/hip_runtime.h>

// LiquidTimeConstantCell fused kernel, MI355X gfx950 — R8.
// Same MFMA layout / math as R6/R7 (transposed MFMA: C row = h, col = batch r,
// bf16 GEMM inputs, fp32 state).
// CHANGES vs R7 (fixing the R7 regression: FETCH 39->247MB from 2x block count):
//   1. Back to ROWS=64, grid=512 (per-block weight reads stay cache-absorbed),
//      but block widened to 512 threads / 8 waves: each wave owns ONE 16-col
//      h-tile (was two). Per-wave VGPR ~110 -> __launch_bounds__(512,4) gives
//      4 waves/SIMD (2 blocks/CU x 8 waves) — R7's occupancy, R6's traffic.
//   2. Keep R7's good parts: double-buffered ldsY (ONE barrier per RK4 stage),
//      deferred ode_out store (drains under stage-1 feval), branchless tanh.

constexpr int kB   = 32768;
constexpr int kH   = 128;
constexpr int kIn  = 128;
constexpr int kT   = 10;
constexpr int ROWS = 64;     // batch rows per block -> 512 blocks (2/CU exactly)
constexpr int NT   = ROWS / 16;   // row tiles per wave = 4
constexpr int LDSW = 136;    // padded bf16 row stride
constexpr int HIN  = 256;    // H + IN

typedef __bf16 bf16;
typedef __attribute__((ext_vector_type(8))) __bf16 bf16x8;
typedef __attribute__((ext_vector_type(4))) __bf16 bf16x4;
typedef __attribute__((ext_vector_type(4))) float  f32x4;

__device__ __forceinline__ float sigmoid_(float v) {
  return __fdividef(1.0f, 1.0f + __expf(-v));
}
// tanh(v) = 1 - 2/(1 + e^{2v}); exact for all v (e=inf -> 1, e=0 -> -1), branchless.
__device__ __forceinline__ float tanh_(float v) {
  float e = __expf(2.0f * v);
  return 1.0f - __fdividef(2.0f, 1.0f + e);
}

__device__ __forceinline__ bf16x8 cvt8(const float* p) {
  float4 f0 = *(const float4*)p;
  float4 f1 = *(const float4*)(p + 4);
  bf16x8 t;
  t[0]=(bf16)f0.x; t[1]=(bf16)f0.y; t[2]=(bf16)f0.z; t[3]=(bf16)f0.w;
  t[4]=(bf16)f1.x; t[5]=(bf16)f1.y; t[6]=(bf16)f1.z; t[7]=(bf16)f1.w;
  return t;
}

// C[nt] += bf16(Wb[hrow][kofs+k]) * S[r][k];  hrow = wave*16 + l16 (A, m=l16),
// r = nt*16 + l16 (B, n=l16), k = kk*32 + quad*8 + j.
__device__ __forceinline__ void gemm4(
    f32x4 (&C)[NT], const bf16 (*S)[LDSW],
    const float* __restrict__ Wb, int ldw, int kofs,
    int wave, int quad, int l16)
{
#pragma unroll
  for (int kk = 0; kk < 4; ++kk) {
    bf16x8 af = cvt8(Wb + (size_t)(wave*16 + l16) * ldw + kofs + kk*32 + quad*8);
#pragma unroll
    for (int nt = 0; nt < NT; ++nt) {
      bf16x8 bfv = *(const bf16x8*)&S[nt*16 + l16][kk*32 + quad*8];
      C[nt] = __builtin_amdgcn_mfma_f32_16x16x32_bf16(af, bfv, C[nt], 0, 0, 0);
    }
  }
}

// K = bias + Weff @ z^T, z read from Y (bf16)
__device__ __forceinline__ void feval(
    f32x4 (&K)[NT], const bf16x8 (&weff)[4], const bf16 (*Y)[LDSW],
    float4 bv, int quad, int l16)
{
#pragma unroll
  for (int nt = 0; nt < NT; ++nt)
    K[nt] = f32x4{bv.x, bv.y, bv.z, bv.w};
#pragma unroll
  for (int kk = 0; kk < 4; ++kk)
#pragma unroll
    for (int nt = 0; nt < NT; ++nt) {
      bf16x8 bfv = *(const bf16x8*)&Y[nt*16 + l16][kk*32 + quad*8];
      K[nt] = __builtin_amdgcn_mfma_f32_16x16x32_bf16(weff[kk], bfv, K[nt], 0, 0, 0);
    }
}

// store V to LDS Y[r][h] as bf16 (LDS only)
__device__ __forceinline__ void storeTile(
    bf16 (*Y)[LDSW], const f32x4 (&V)[NT], int hc0, int l16)
{
#pragma unroll
  for (int nt = 0; nt < NT; ++nt) {
    bf16x4 p;
    p[0]=(bf16)V[nt][0]; p[1]=(bf16)V[nt][1];
    p[2]=(bf16)V[nt][2]; p[3]=(bf16)V[nt][3];
    *(bf16x4*)&Y[nt*16 + l16][hc0] = p;
  }
}

// store V to global fp32, row-major [r][h], gbase pre-offset to block rows
__device__ __forceinline__ void storeGlob(
    float* gbase, const f32x4 (&V)[NT], int hc0, int l16)
{
#pragma unroll
  for (int nt = 0; nt < NT; ++nt) {
    float4 g{V[nt][0], V[nt][1], V[nt][2], V[nt][3]};
    *(float4*)(gbase + (size_t)(nt*16 + l16) * kH + hc0) = g;
  }
}

__global__ __launch_bounds__(512, 4) void ltc_kernel(
    const float* __restrict__ x,     const float* __restrict__ hidden,
    const float* __restrict__ ts,    const float* __restrict__ wiring,
    const float* __restrict__ W,     const float* __restrict__ bb_,
    const float* __restrict__ W_in,  const float* __restrict__ b_in,
    const float* __restrict__ W_upd, const float* __restrict__ b_upd,
    const float* __restrict__ W_rst, const float* __restrict__ b_rst,
    float* __restrict__ out)   // FP32 output: [new_hidden (B,H); ode_out (T,B,H)]
{
  __shared__ bf16 ldsX [ROWS][LDSW];   // x tile; later h0 (bf16)
  __shared__ bf16 ldsHd[ROWS][LDSW];   // hidden tile; later u (bf16)
  __shared__ bf16 ldsY0[ROWS][LDSW];   // ODE state z, ping
  __shared__ bf16 ldsY1[ROWS][LDSW];   // ODE state z, pong
  __shared__ float sts[kT];

  const int tid  = threadIdx.x;
  const int wave = tid >> 6;           // 0..7: h-column tile
  const int lane = tid & 63;
  const int quad = lane >> 4;
  const int l16  = lane & 15;
  const int r0   = blockIdx.x * ROWS;

  if (tid < kT) sts[tid] = ts[tid];

  // ---- stage x & hidden tiles into LDS as bf16 (512 threads, 64x32 float4) ----
#pragma unroll
  for (int i = 0; i < 4; ++i) {
    int idx = i*512 + tid;            // float4 index in 64x32
    int row = idx >> 5;
    int c4  = (idx & 31) * 4;
    float4 vx = *(const float4*)(x      + (size_t)(r0+row)*kIn + c4);
    float4 vh = *(const float4*)(hidden + (size_t)(r0+row)*kH  + c4);
    bf16x4 bx; bx[0]=(bf16)vx.x; bx[1]=(bf16)vx.y; bx[2]=(bf16)vx.z; bx[3]=(bf16)vx.w;
    bf16x4 bh; bh[0]=(bf16)vh.x; bh[1]=(bf16)vh.y; bh[2]=(bf16)vh.z; bh[3]=(bf16)vh.w;
    *(bf16x4*)&ldsX [row][c4] = bx;
    *(bf16x4*)&ldsHd[row][c4] = bh;
  }

  const int hc0 = wave*16 + quad*4;    // lane's C-tile h base (4 cols)

  // ---- persistent W_eff = W .* wiring, A-fragments (16 VGPRs) ----
  bf16x8 weff[4];
  {
    int hrow = wave*16 + l16;
#pragma unroll
    for (int kk = 0; kk < 4; ++kk) {
      int k = kk*32 + quad*8;
      const float* wp = W      + (size_t)hrow*kH + k;
      const float* mp = wiring + (size_t)hrow*kH + k;
      float4 w0 = *(const float4*)wp, w1 = *(const float4*)(wp+4);
      float4 m0 = *(const float4*)mp, m1 = *(const float4*)(mp+4);
      bf16x8 t;
      t[0]=(bf16)(w0.x*m0.x); t[1]=(bf16)(w0.y*m0.y);
      t[2]=(bf16)(w0.z*m0.z); t[3]=(bf16)(w0.w*m0.w);
      t[4]=(bf16)(w1.x*m1.x); t[5]=(bf16)(w1.y*m1.y);
      t[6]=(bf16)(w1.z*m1.z); t[7]=(bf16)(w1.w*m1.w);
      weff[kk] = t;
    }
  }
  float4 bv = *(const float4*)(bb_ + hc0);

  __syncthreads();   // x/hidden tiles visible

  // ---- x_proj (persistent regs) ----
  f32x4 xp[NT];
  {
    float4 bi = *(const float4*)(b_in + hc0);
#pragma unroll
    for (int nt = 0; nt < NT; ++nt)
      xp[nt] = f32x4{bi.x, bi.y, bi.z, bi.w};
    gemm4(xp, ldsX, W_in, kIn, 0, wave, quad, l16);
  }

  // ---- both gates up front ----
  f32x4 h[NT], U[NT];
  {
    f32x4 R[NT];
    float4 br = *(const float4*)(b_rst + hc0);
    float4 bu = *(const float4*)(b_upd + hc0);
#pragma unroll
    for (int nt = 0; nt < NT; ++nt) {
      R[nt] = f32x4{br.x, br.y, br.z, br.w};
      U[nt] = f32x4{bu.x, bu.y, bu.z, bu.w};
    }
    gemm4(R, ldsHd, W_rst, HIN, 0,  wave, quad, l16);
    gemm4(R, ldsX,  W_rst, HIN, kH, wave, quad, l16);
    gemm4(U, ldsHd, W_upd, HIN, 0,  wave, quad, l16);
    gemm4(U, ldsX,  W_upd, HIN, kH, wave, quad, l16);

#pragma unroll
    for (int nt = 0; nt < NT; ++nt) {
      const float* hp = hidden + (size_t)(r0 + nt*16 + l16)*kH + hc0;
      float4 hv = *(const float4*)hp;
      h[nt][0] = sigmoid_(R[nt][0]) * hv.x;   // h0
      h[nt][1] = sigmoid_(R[nt][1]) * hv.y;
      h[nt][2] = sigmoid_(R[nt][2]) * hv.z;
      h[nt][3] = sigmoid_(R[nt][3]) * hv.w;
      U[nt][0] = sigmoid_(U[nt][0]);          // u
      U[nt][1] = sigmoid_(U[nt][1]);
      U[nt][2] = sigmoid_(U[nt][2]);
      U[nt][3] = sigmoid_(U[nt][3]);
    }
  }

  __syncthreads();   // gate GEMM reads of ldsX/ldsHd done -> tiles reusable

  // park u and h0 in the now-dead tiles (bf16), freeing registers for the loop
  storeTile(ldsHd, U, hc0, l16);
  storeTile(ldsX,  h, hc0, l16);
  storeTile(ldsY0, h, hc0, l16);      // z = h0 (ping buffer)

  f32x4 z[NT], hacc[NT], K[NT];
#pragma unroll
  for (int nt = 0; nt < NT; ++nt) z[nt] = h[nt];

  float* odeBase = out + (size_t)kB*kH + (size_t)r0*kH;

  for (int t = 1; t < kT; ++t) {
    float dt  = sts[t] - sts[t-1];   // via LDS (R1: uniform global read ISel bug)
    float dt6 = dt * (1.0f/6.0f);
    float dt3 = dt * (1.0f/3.0f);
    float dth = 0.5f * dt;

    // ---- stage 1: read Y0, write Y1 ----
    __syncthreads();
    // deferred ode_out[t-1] = h_{t-1}: drains under this stage's feval+pointwise
    storeGlob(odeBase + (size_t)(t-1)*kB*kH, h, hc0, l16);
    feval(K, weff, ldsY0, bv, quad, l16);
#pragma unroll
    for (int nt = 0; nt < NT; ++nt)
#pragma unroll
      for (int i = 0; i < 4; ++i) {
        float kv = tanh_(K[nt][i]) + xp[nt][i] - z[nt][i];
        hacc[nt][i] = h[nt][i] + dt6 * kv;
        z[nt][i]    = h[nt][i] + dth * kv;
      }
    storeTile(ldsY1, z, hc0, l16);

    // ---- stage 2: read Y1, write Y0 ----
    __syncthreads();
    feval(K, weff, ldsY1, bv, quad, l16);
#pragma unroll
    for (int nt = 0; nt < NT; ++nt)
#pragma unroll
      for (int i = 0; i < 4; ++i) {
        float kv = tanh_(K[nt][i]) + xp[nt][i] - z[nt][i];
        hacc[nt][i] += dt3 * kv;
        z[nt][i]     = h[nt][i] + dth * kv;
      }
    storeTile(ldsY0, z, hc0, l16);

    // ---- stage 3: read Y0, write Y1 ----
    __syncthreads();
    feval(K, weff, ldsY0, bv, quad, l16);
#pragma unroll
    for (int nt = 0; nt < NT; ++nt)
#pragma unroll
      for (int i = 0; i < 4; ++i) {
        float kv = tanh_(K[nt][i]) + xp[nt][i] - z[nt][i];
        hacc[nt][i] += dt3 * kv;
        z[nt][i]     = h[nt][i] + dt * kv;
      }
    storeTile(ldsY1, z, hc0, l16);

    // ---- stage 4: read Y1, write Y0 ----
    __syncthreads();
    feval(K, weff, ldsY1, bv, quad, l16);
#pragma unroll
    for (int nt = 0; nt < NT; ++nt)
#pragma unroll
      for (int i = 0; i < 4; ++i) {
        float kv = tanh_(K[nt][i]) + xp[nt][i] - z[nt][i];
        h[nt][i] = hacc[nt][i] + dt6 * kv;
        z[nt][i] = h[nt][i];
      }
    storeTile(ldsY0, z, hc0, l16);   // next step's stage 1 reads Y0
  }

  // last ode slab: ode_out[T-1] = h_last
  storeGlob(odeBase + (size_t)(kT-1)*kB*kH, h, hc0, l16);

  // ---- final blend: new_hidden = u*h_last + (1-u)*h0 (fp32 store) ----
  // parked u/h0 rectangles were written by this same wave -> no barrier needed
#pragma unroll
  for (int nt = 0; nt < NT; ++nt) {
    int r = nt*16 + l16;
    bf16x4 uv  = *(const bf16x4*)&ldsHd[r][hc0];
    bf16x4 h0v = *(const bf16x4*)&ldsX [r][hc0];
    float4 p;
    {
      float uu;
      uu = (float)uv[0]; p.x = uu * h[nt][0] + (1.0f - uu) * (float)h0v[0];
      uu = (float)uv[1]; p.y = uu * h[nt][1] + (1.0f - uu) * (float)h0v[1];
      uu = (float)uv[2]; p.z = uu * h[nt][2] + (1.0f - uu) * (float)h0v[2];
      uu = (float)uv[3]; p.w = uu * h[nt][3] + (1.0f - uu) * (float)h0v[3];
    }
    *(float4*)(out + (size_t)(r0 + r) * kH + hc0) = p;
  }
}

extern "C" void kernel_launch(void* const* d_in, const int* in_sizes, int n_in,
                              void* d_out, int out_size, void* d_ws, size_t ws_size,
                              hipStream_t stream) {
  (void)d_ws; (void)ws_size; (void)out_size;
  // Resolve input order from in_sizes (insurance; documented order expected).
  int ix=0, ih=1, its=2, iwr=3, iW=4, ib=5, iWin=6, ibin=7, iWu=8, ibu=9, iWr=10, ibr=11;
  if (n_in == 12 && in_sizes[2] != 10 && in_sizes[5] == 10) {
    // case-insensitive name-sorted: b,b_in,b_rst,b_upd,hidden,time_span,W,W_in,W_rst,W_upd,wiring,x
    ib=0; ibin=1; ibr=2; ibu=3; ih=4; its=5; iW=6; iWin=7; iWr=8; iWu=9; iwr=10; ix=11;
  }
  const float* x      = (const float*)d_in[ix];
  const float* hidden = (const float*)d_in[ih];
  const float* ts     = (const float*)d_in[its];
  const float* wiring = (const float*)d_in[iwr];
  const float* W      = (const float*)d_in[iW];
  const float* b      = (const float*)d_in[ib];
  const float* W_in   = (const float*)d_in[iWin];
  const float* b_in   = (const float*)d_in[ibin];
  const float* W_upd  = (const float*)d_in[iWu];
  const float* b_upd  = (const float*)d_in[ibu];
  const float* W_rst  = (const float*)d_in[iWr];
  const float* b_rst  = (const float*)d_in[ibr];

  dim3 grid(kB / ROWS);   // 512 blocks -> 2 blocks/CU, 8 waves each
  dim3 block(512);
  ltc_kernel<<<grid, block, 0, stream>>>(x, hidden, ts, wiring, W, b,
                                         W_in, b_in, W_upd, b_upd, W_rst, b_rst,
                                         (float*)d_out);
}